// Round 3
// baseline (16232.927 us; speedup 1.0000x reference)
//
#include <hip/hip_runtime.h>

typedef _Float16 f16;
typedef _Float16 h2 __attribute__((ext_vector_type(2)));
typedef _Float16 h4 __attribute__((ext_vector_type(4)));
typedef _Float16 h8 __attribute__((ext_vector_type(8)));

#define T127 127

__device__ __forceinline__ float rcp_f(float x) { return __builtin_amdgcn_rcpf(x); }

__device__ __forceinline__ float fdot2(h2 a, h2 b, float c) {
  return __builtin_amdgcn_fdot2(a, b, c, false);
}
__device__ __forceinline__ h2 mk2(f16 a, f16 b) { h2 v; v[0] = a; v[1] = b; return v; }

__device__ __forceinline__ float fast_tanh(float x) {
  x = fminf(fmaxf(x, -12.f), 12.f);
  float e = __expf(2.f * x);
  return (e - 1.f) * rcp_f(e + 1.f);
}
__device__ __forceinline__ float fast_sig(float x) {
  x = fminf(fmaxf(x, -30.f), 30.f);
  return rcp_f(1.f + __expf(-x));
}

// LDS-only barrier: drains lgkmcnt (DS ops) but NOT vmcnt, so global
// prefetch loads stay in flight across the barrier. Only LDS carries
// cross-wave data in the step loop, so this is sufficient.
__device__ __forceinline__ void bar_lds() {
  asm volatile("s_waitcnt lgkmcnt(0)" ::: "memory");
  __builtin_amdgcn_s_barrier();
  asm volatile("" ::: "memory");
}

// ---- pack Wa1 h+c parts fp32 -> fp16 single u-stream ----
// wsU[(it*512 + L)*8 + j] = Wa1[L>>1][(it>>4)*256 + (L&1)*128 + (it&15)*8 + j]
// it 0..15: h-cols; it 16..31: c-cols. 256 KB.
__global__ void pack_wsU(const float* __restrict__ Wa1, f16* __restrict__ wsU) {
  int tid = blockIdx.x * 256 + threadIdx.x;  // 64 blocks
  int it = tid >> 9, L = tid & 511;
  int kL = L >> 1, g2 = L & 1;
  const float* src = Wa1 + (size_t)kL * 768 + (it >> 4) * 256 + g2 * 128 + (it & 15) * 8;
  f16* dst = wsU + (size_t)tid * 8;
#pragma unroll
  for (int j = 0; j < 8; ++j) dst[j] = (f16)src[j];
}

// ---- pack Whh fp32 -> fp16, per-cell 4-gate contiguous stream ----
// wsH[((i*256 + kk)*4 + g)*8 + j] = Whh[(g*256+kk)*256 + i*8 + j]
// Per k-chunk i, a lane owning cell kk loads its 4 gate-weights from 64
// contiguous bytes; a wave (32 cells) covers 2 KB contiguous. 512 KB.
__global__ void pack_wsH(const float* __restrict__ Whh, f16* __restrict__ wsH) {
  int tid = blockIdx.x * 256 + threadIdx.x;  // 128 blocks -> 32768
  int i = tid >> 10, kk = (tid >> 2) & 255, g = tid & 3;
  const float* src = Whh + (size_t)(g * 256 + kk) * 256 + i * 8;
  f16* dst = wsH + (size_t)tid * 8;
#pragma unroll
  for (int j = 0; j < 8; ++j) dst[j] = (f16)src[j];
}

// 256 blocks x 512 threads, 1 block/CU (LDS-limited).
// Round-10: rounds 8/9 spilled catastrophically (WRITE 32MB->15.7GB) because
// the 512-thread-WG default VGPR cap is 128 and the deep-prefetch working
// set (aw[8]=32 + W[4][4]=64 + 12 accs) needs ~180. amdgpu_waves_per_eu(2)
// was IGNORED (codegen bit-identical). Fix: (a) shrink working set to fit
// 128 regardless -- aw 8->4-deep, W 4->2-deep (~100 VGPR steady state, the
// depth round-0 ran spill-free at); (b) request the budget via the
// battle-tested __launch_bounds__(512, 2) spelling (min 2 waves/EU -> 256
// cap if honored). Keeps split-K Whh, conflict-free tE1 geometry, full
// unroll, and vmcnt-preserving barriers from round-8.
__global__ void __launch_bounds__(512, 2) decoder_kernel(
    const float* __restrict__ enc,    // [512][127][256]
    const float* __restrict__ yhist,  // [512][127]
    const float* __restrict__ Wa1,    // [256][768] (prologue only)
    const float* __restrict__ ba1,    // [256]
    const float* __restrict__ Wa2,    // [256]
    const float* __restrict__ ba2,    // [1]
    const float* __restrict__ Wih,    // [1024]
    const float* __restrict__ bih,    // [1024]
    const float* __restrict__ bhh,    // [1024]
    const float* __restrict__ Wfc,    // [257]
    const float* __restrict__ bfc,    // [1]
    const float* __restrict__ Wfcf,   // [512]
    const float* __restrict__ bfcf,   // [1]
    const f16* __restrict__ wsU,      // packed Wa1 h|c [32][512][8]
    const f16* __restrict__ wsH,      // packed Whh [32][256][4][8]
    float* __restrict__ outp)         // [512] out ++ [512][127][127] weight
{
  // tE1 flat: b*34592 + j*272 + g*68 + e (halves). Row = 4 chunks x 68.
  // 272-half rows (136 words = 8 mod 32) + batch stride 34592 halves
  // (16 mod 32 words) -> conflict-free b64 reads.
  __shared__ __align__(16) f16 tE1[2 * 34592];
  __shared__ __align__(16) f16 hch[2][4][136];      // h (chunks 0,1) | c (2,3) fp16
  __shared__ __align__(16) float s_arr[2][4][68];   // s = tanh(u+b1)
  __shared__ __align__(16) float score_s[2][128];
  __shared__ __align__(16) float p_s[2][128];       // e . Wfc[0:256]
  __shared__ __align__(16) float q_s[2][128];       // e . Wfcf[256:512]
  __shared__ __align__(16) f16 est[8][288];         // prologue staging
  __shared__ __align__(16) float w2_lds[256];
  __shared__ __align__(16) float yh_s[2][128];
  __shared__ float ctxq_s[2], red2[16];

  const int L = threadIdx.x;   // 0..511
  const int b0 = blockIdx.x * 2;
  const int kL = L >> 1;       // u-output index 0..255
  const int g2 = L & 1;        // col-half / K-half selector
  const int kk2 = L >> 1;      // owned LSTM cell
  const int bbE = L & 1;       // owned batch (cell state)
  const int g_u = L & 3;

  // ---------------- init ----------------
  for (int i = L; i < 1088; i += 512) ((f16*)hch)[i] = (f16)0.f;
  if (L < 256) {
    w2_lds[L] = Wa2[L];
    int bb = L >> 7, tt = L & 127;
    if (tt < T127) yh_s[bb][tt] = yhist[(size_t)(b0 + bb) * T127 + tt];
  }
  float c_reg = 0.f;  // fp32 cell state for (bbE, kk2)

  // ---------------- prologue: tE1 = tanh(e.W1e), p, q ----------------
  {
    h2 we1[64];  // W1e[kL][g2*128 .. +128]
    {
      const float4* wrow = (const float4*)(Wa1 + (size_t)kL * 768 + 512 + g2 * 128);
#pragma unroll
      for (int i = 0; i < 32; ++i) {
        float4 w = wrow[i];
        we1[2 * i]     = mk2((f16)w.x, (f16)w.y);
        we1[2 * i + 1] = mk2((f16)w.z, (f16)w.w);
      }
    }
    const int prow = L >> 6;      // wave id = staged row 0..7
    const int lm = L & 63;
    const int sg = lm >> 4;       // staging chunk 0..3 (72-elem stride)
    const int si = (lm * 4) & 63;

#pragma unroll 1
    for (int tt = 0; tt < 32; ++tt) {
      __syncthreads();
      {  // stage 8 (b,j) rows as fp16: row = bbs*4 + j4, j = tt*4+j4
        int bbs = prow >> 2, j4 = prow & 3, j = tt * 4 + j4;
        float4 v = make_float4(0.f, 0.f, 0.f, 0.f);
        if (j < T127)
          v = *(const float4*)(enc + (((size_t)(b0 + bbs)) * T127 + j) * 256 + lm * 4);
        h4 hv; hv[0] = (f16)v.x; hv[1] = (f16)v.y; hv[2] = (f16)v.z; hv[3] = (f16)v.w;
        *(h4*)(&est[prow][0] + sg * 72 + si) = hv;
      }
      __syncthreads();
#pragma unroll 1
      for (int P = 0; P < 8; ++P) {
        int bbs = P >> 2, j4 = P & 3, j = tt * 4 + j4;
        const h8* ep = (const h8*)(&est[P][0] + (2 * g2) * 72);
        const h8* ep2 = (const h8*)(&est[P][0] + (2 * g2 + 1) * 72);
        float a0 = 0.f, a1 = 0.f;
#pragma unroll
        for (int r = 0; r < 8; ++r) {
          h8 e8 = ep[r];
          a0 = fdot2(we1[4 * r + 0], mk2(e8[0], e8[1]), a0);
          a1 = fdot2(we1[4 * r + 1], mk2(e8[2], e8[3]), a1);
          a0 = fdot2(we1[4 * r + 2], mk2(e8[4], e8[5]), a0);
          a1 = fdot2(we1[4 * r + 3], mk2(e8[6], e8[7]), a1);
        }
#pragma unroll
        for (int r = 0; r < 8; ++r) {
          h8 e8 = ep2[r];
          a0 = fdot2(we1[32 + 4 * r + 0], mk2(e8[0], e8[1]), a0);
          a1 = fdot2(we1[32 + 4 * r + 1], mk2(e8[2], e8[3]), a1);
          a0 = fdot2(we1[32 + 4 * r + 2], mk2(e8[4], e8[5]), a0);
          a1 = fdot2(we1[32 + 4 * r + 3], mk2(e8[6], e8[7]), a1);
        }
        float acc = a0 + a1;
        acc += __shfl_xor(acc, 1, 64);
        if (g2 == 0 && j < T127)
          tE1[bbs * 34592 + j * 272 + (kL >> 6) * 68 + (kL & 63)] = (f16)fast_tanh(acc);
      }
      {  // p, q for this wave's staged row
        int bbs = prow >> 2, j4 = prow & 3, j = tt * 4 + j4;
        float4 wp4 = *(const float4*)(Wfc + lm * 4);
        float4 wq4 = *(const float4*)(Wfcf + 256 + lm * 4);
        h4 ev = *(const h4*)(&est[prow][0] + sg * 72 + si);
        float pacc = (float)ev[0] * wp4.x + (float)ev[1] * wp4.y + (float)ev[2] * wp4.z + (float)ev[3] * wp4.w;
        float qacc = (float)ev[0] * wq4.x + (float)ev[1] * wq4.y + (float)ev[2] * wq4.z + (float)ev[3] * wq4.w;
#pragma unroll
        for (int s = 32; s; s >>= 1) {
          pacc += __shfl_xor(pacc, s, 64);
          qacc += __shfl_xor(qacc, s, 64);
        }
        if (lm == 0 && j < T127) { p_s[bbs][j] = pacc; q_s[bbs][j] = qacc; }
      }
    }
  }
  __syncthreads();

  // ---------------- persistent per-lane constants ----------------
  const float b1k = ba1[kL];
  const float wih0 = Wih[kk2];            // gate i row
  const float wih1 = Wih[256 + kk2];      // f
  const float wih2 = Wih[512 + kk2];      // g
  const float wih3 = Wih[768 + kk2];      // o
  const float bia0 = bih[kk2] + bhh[kk2];
  const float bia1 = bih[256 + kk2] + bhh[256 + kk2];
  const float bia2 = bih[512 + kk2] + bhh[512 + kk2];
  const float bia3 = bih[768 + kk2] + bhh[768 + kk2];
  const float ba2v = ba2[0];
  const float wfcy = Wfc[256];
  const float bfc0 = bfc[0];
  const float wfcf_k = Wfcf[kk2];

  // ---------------- stream / score pointers ----------------
  const h8* wp = (const h8*)wsU + L;                                 // u-stream
  const h8* wb = (const h8*)wsH + ((size_t)g2 * 16 * 256 + kk2) * 4; // Whh stream
  const f16* hxb = (const f16*)hch + g2 * 136;  // own K-half chunk base (batch0)

  const int prA = L >> 2;                  // score row, first pass (0..127)
  const int bbA = prA & 1, jA = prA >> 1;
  const int prB = prA + 128;               // second pass
  const int prC = prB < 254 ? prB : 253;
  const int bbB2 = prC & 1, jB2 = prC >> 1;
  const h4* tpA = (const h4*)(tE1 + bbA * 34592 + jA * 272 + g_u * 68);
  const h4* tpB = (const h4*)(tE1 + bbB2 * 34592 + jB2 * 272 + g_u * 68);
  const float4* spA = (const float4*)&s_arr[bbA][g_u][0];
  const float4* spB = (const float4*)&s_arr[bbB2][g_u][0];
  const float4* w2p = (const float4*)&w2_lds[g_u * 64];

  // A1 u-stream prefetch for t=0 (4-deep)
  h8 aw[4];
#pragma unroll
  for (int k = 0; k < 4; ++k) aw[k] = wp[k * 512];

  // ---------------- 127 sequential steps ----------------
#pragma unroll 1
  for (int t = 0; t < T127; ++t) {
    // ---- Phase A1: u = Wa1.[h;c], fully unrolled, 4-deep prefetch ----
    float u0a = 0.f, u0b = 0.f, u1a = 0.f, u1b = 0.f;
#pragma unroll
    for (int it = 0; it < 32; ++it) {
      h8 a0 = aw[it & 3];
      if (it < 28) aw[it & 3] = wp[(it + 4) * 512];
      const f16* hp = hxb + (it >> 4) * 272 + (it & 15) * 8;
      h8 x = *(const h8*)hp;           // batch 0
      h8 y = *(const h8*)(hp + 544);   // batch 1
      u0a = fdot2(mk2(a0[0], a0[1]), mk2(x[0], x[1]), u0a);
      u0b = fdot2(mk2(a0[2], a0[3]), mk2(x[2], x[3]), u0b);
      u0a = fdot2(mk2(a0[4], a0[5]), mk2(x[4], x[5]), u0a);
      u0b = fdot2(mk2(a0[6], a0[7]), mk2(x[6], x[7]), u0b);
      u1a = fdot2(mk2(a0[0], a0[1]), mk2(y[0], y[1]), u1a);
      u1b = fdot2(mk2(a0[2], a0[3]), mk2(y[2], y[3]), u1b);
      u1a = fdot2(mk2(a0[4], a0[5]), mk2(y[4], y[5]), u1a);
      u1b = fdot2(mk2(a0[6], a0[7]), mk2(y[6], y[7]), u1b);
    }
    {
      float u0 = u0a + u0b, u1 = u1a + u1b;
      u0 += __shfl_xor(u0, 1, 64);
      u1 += __shfl_xor(u1, 1, 64);
      if (g2 == 0) s_arr[0][kL >> 6][kL & 63] = fast_tanh(u0 + b1k);
      else         s_arr[1][kL >> 6][kL & 63] = fast_tanh(u1 + b1k);
    }
    // fused W prefetch (2-deep), issued BEFORE the barrier: latency
    // overlaps the barrier wait (bar_lds does not drain vmcnt).
    h8 W[2][4];
#pragma unroll
    for (int d = 0; d < 2; ++d) {
#pragma unroll
      for (int g = 0; g < 4; ++g) W[d][g] = wb[d * 1024 + g];
    }
    bar_lds();  // #1: s_arr visible

    // ---- Fused: split-K Whh (4 gates x 2 batches) + attn scores ----
    float ghA0 = 0.f, ghA1 = 0.f, ghA2 = 0.f, ghA3 = 0.f;  // batch 0, own K-half
    float ghB0 = 0.f, ghB1 = 0.f, ghB2 = 0.f, ghB3 = 0.f;  // batch 1, own K-half
    float accA0 = 0.f, accA1 = 0.f, accB0 = 0.f, accB1 = 0.f;

#define GH8(acc, w, v)                                   \
    acc = fdot2(mk2(w[0], w[1]), mk2(v[0], v[1]), acc);  \
    acc = fdot2(mk2(w[2], w[3]), mk2(v[2], v[3]), acc);  \
    acc = fdot2(mk2(w[4], w[5]), mk2(v[4], v[5]), acc);  \
    acc = fdot2(mk2(w[6], w[7]), mk2(v[6], v[7]), acc);

#pragma unroll
    for (int ii = 0; ii < 16; ++ii) {
      h8 w0 = W[ii & 1][0], w1 = W[ii & 1][1];
      h8 w2r = W[ii & 1][2], w3r = W[ii & 1][3];
      if (ii < 14) {
#pragma unroll
        for (int g = 0; g < 4; ++g) W[ii & 1][g] = wb[(ii + 2) * 1024 + g];
      }
      h8 x = *(const h8*)(hxb + ii * 8);          // batch 0, chunk g2*16+ii
      h8 y = *(const h8*)(hxb + 544 + ii * 8);    // batch 1
      GH8(ghA0, w0, x)  GH8(ghB0, w0, y)
      GH8(ghA1, w1, x)  GH8(ghB1, w1, y)
      GH8(ghA2, w2r, x) GH8(ghB2, w2r, y)
      GH8(ghA3, w3r, x) GH8(ghB3, w3r, y)
      {
        float4 wv = w2p[ii];
        h4 tv = tpA[ii];
        float4 sv = spA[ii];
        float t0 = (float)tv[0], t1 = (float)tv[1];
        float t2 = (float)tv[2], t3 = (float)tv[3];
        accA0 = fmaf(wv.x * (sv.x + t0), rcp_f(fmaf(sv.x, t0, 1.f)), accA0);
        accA1 = fmaf(wv.y * (sv.y + t1), rcp_f(fmaf(sv.y, t1, 1.f)), accA1);
        accA0 = fmaf(wv.z * (sv.z + t2), rcp_f(fmaf(sv.z, t2, 1.f)), accA0);
        accA1 = fmaf(wv.w * (sv.w + t3), rcp_f(fmaf(sv.w, t3, 1.f)), accA1);
        h4 tw = tpB[ii];
        float4 sw = spB[ii];
        float r0 = (float)tw[0], r1 = (float)tw[1];
        float r2 = (float)tw[2], r3 = (float)tw[3];
        accB0 = fmaf(wv.x * (sw.x + r0), rcp_f(fmaf(sw.x, r0, 1.f)), accB0);
        accB1 = fmaf(wv.y * (sw.y + r1), rcp_f(fmaf(sw.y, r1, 1.f)), accB1);
        accB0 = fmaf(wv.z * (sw.z + r2), rcp_f(fmaf(sw.z, r2, 1.f)), accB0);
        accB1 = fmaf(wv.w * (sw.w + r3), rcp_f(fmaf(sw.w, r3, 1.f)), accB1);
      }
    }
#undef GH8
    {
      float accA = accA0 + accA1;
      accA += __shfl_xor(accA, 1, 64);
      accA += __shfl_xor(accA, 2, 64);
      if (g_u == 0) score_s[bbA][jA] = accA + ba2v;
      float accB = accB0 + accB1;
      accB += __shfl_xor(accB, 1, 64);
      accB += __shfl_xor(accB, 2, 64);
      if (g_u == 0 && prB < 254) score_s[bbB2][jB2] = accB + ba2v;
    }
    // pair-combine K-halves: lane's own batch is bbE==g2; partner holds
    // the other K-half of my batch in its same-named accumulator.
    float gh0, gh1, gh2, gh3;
    {
      float s0 = g2 ? ghA0 : ghB0, k0 = g2 ? ghB0 : ghA0;
      float s1 = g2 ? ghA1 : ghB1, k1 = g2 ? ghB1 : ghA1;
      float s2 = g2 ? ghA2 : ghB2, k2v = g2 ? ghB2 : ghA2;
      float s3 = g2 ? ghA3 : ghB3, k3 = g2 ? ghB3 : ghA3;
      gh0 = k0 + __shfl_xor(s0, 1, 64);
      gh1 = k1 + __shfl_xor(s1, 1, 64);
      gh2 = k2v + __shfl_xor(s2, 1, 64);
      gh3 = k3 + __shfl_xor(s3, 1, 64);
    }
    bar_lds();  // #2: score_s visible

    // ---- Phase C: redundant per-wave softmax, interleaved reductions ----
    float ytil0, ytil1;
    float ra, rb;
    {
      const int ln = L & 63;
      const int wv = L >> 6;
      float e0a = __expf(score_s[0][ln]);
      float e1a = (ln < 63) ? __expf(score_s[0][64 + ln]) : 0.f;
      float e0b = __expf(score_s[1][ln]);
      float e1b = (ln < 63) ? __expf(score_s[1][64 + ln]) : 0.f;
      float sa = e0a + e1a, sb = e0b + e1b;
      float cwa = e0a * p_s[0][ln] + ((ln < 63) ? e1a * p_s[0][64 + ln] : 0.f);
      float cwb = e0b * p_s[1][ln] + ((ln < 63) ? e1b * p_s[1][64 + ln] : 0.f);
#pragma unroll
      for (int s = 32; s; s >>= 1) {
        sa += __shfl_xor(sa, s, 64);
        sb += __shfl_xor(sb, s, 64);
        cwa += __shfl_xor(cwa, s, 64);
        cwb += __shfl_xor(cwb, s, 64);
      }
      ra = rcp_f(sa); rb = rcp_f(sb);
      if (wv == 0) {
        float* wout = outp + 512 + ((size_t)b0 * T127 + t) * T127;
        wout[ln] = e0a * ra;
        if (ln < 63) wout[64 + ln] = e1a * ra;
      } else if (wv == 1) {
        float* wout = outp + 512 + ((size_t)(b0 + 1) * T127 + t) * T127;
        wout[ln] = e0b * rb;
        if (ln < 63) wout[64 + ln] = e1b * rb;
      }
      ytil0 = cwa * ra + wfcy * yh_s[0][t] + bfc0;
      ytil1 = cwb * rb + wfcy * yh_s[1][t] + bfc0;
      if (t == T127 - 1) {
        float cqa = e0a * q_s[0][ln] + ((ln < 63) ? e1a * q_s[0][64 + ln] : 0.f);
        float cqb = e0b * q_s[1][ln] + ((ln < 63) ? e1b * q_s[1][64 + ln] : 0.f);
#pragma unroll
        for (int s = 32; s; s >>= 1) {
          cqa += __shfl_xor(cqa, s, 64);
          cqb += __shfl_xor(cqb, s, 64);
        }
        if (L == 0) { ctxq_s[0] = cqa * ra; ctxq_s[1] = cqb * rb; }
      }
    }

    // ---- Phase D+E fused: gates + cell update, all in-lane ----
    {
      float yt = bbE ? ytil1 : ytil0;
      float g_i = gh0 + wih0 * yt + bia0;
      float g_f = gh1 + wih1 * yt + bia1;
      float g_g = gh2 + wih2 * yt + bia2;
      float g_o = gh3 + wih3 * yt + bia3;
      float ai = fast_sig(g_i);
      float af = fast_sig(g_f);
      float ag = fast_tanh(g_g);
      float ao = fast_sig(g_o);
      float cn = af * c_reg + ai * ag;
      float hn = ao * fast_tanh(cn);
      c_reg = cn;
      hch[bbE][kk2 >> 7][kk2 & 127] = (f16)hn;
      hch[bbE][2 + (kk2 >> 7)][kk2 & 127] = (f16)cn;
      if (t == T127 - 1) {
        float po = wfcf_k * hn;
        po += __shfl_xor(po, 32, 64);
        po += __shfl_xor(po, 16, 64);
        po += __shfl_xor(po, 8, 64);
        po += __shfl_xor(po, 4, 64);
        po += __shfl_xor(po, 2, 64);
        if ((L & 63) < 2) red2[(L >> 6) * 2 + (L & 1)] = po;
      }
    }
    // A1 u-stream prefetch for next step, before the barrier (stays in
    // flight across it).
    if (t + 1 < T127) {
#pragma unroll
      for (int k = 0; k < 4; ++k) aw[k] = wp[k * 512];
    }
    bar_lds();  // #3: hch (+ red2/ctxq on last step) visible
  }

  // ---------------- final: out = Wfcf[0:256].h + ctx.Wfcf[256:512] + b ----------------
  if (L < 2) {
    float o = ctxq_s[L] + bfcf[0];
#pragma unroll
    for (int w = 0; w < 8; ++w) o += red2[w * 2 + L];
    outp[b0 + L] = o;
  }
}

extern "C" void kernel_launch(void* const* d_in, const int* in_sizes, int n_in,
                              void* d_out, int out_size, void* d_ws, size_t ws_size,
                              hipStream_t stream) {
  (void)in_sizes; (void)n_in; (void)out_size; (void)ws_size;
  f16* wsU = (f16*)d_ws;            // 32*512*8 = 131072 halves (256 KiB)
  f16* wsH = wsU + 131072;          // 32*256*4*8 = 262144 halves (512 KiB)
  pack_wsU<<<64, 256, 0, stream>>>((const float*)d_in[2], wsU);
  pack_wsH<<<128, 256, 0, stream>>>((const float*)d_in[7], wsH);
  decoder_kernel<<<256, 512, 0, stream>>>(
      (const float*)d_in[0], (const float*)d_in[1], (const float*)d_in[2],
      (const float*)d_in[3], (const float*)d_in[4], (const float*)d_in[5],
      (const float*)d_in[6], (const float*)d_in[8], (const float*)d_in[9],
      (const float*)d_in[10], (const float*)d_in[11], (const float*)d_in[12],
      (const float*)d_in[13], wsU, wsH, (float*)d_out);
}

// Round 4
// 1636.082 us; speedup vs baseline: 9.9218x; 9.9218x over previous
//
#include <hip/hip_runtime.h>

typedef _Float16 f16;
typedef _Float16 h2 __attribute__((ext_vector_type(2)));
typedef _Float16 h4 __attribute__((ext_vector_type(4)));
typedef _Float16 h8 __attribute__((ext_vector_type(8)));

#define T127 127

__device__ __forceinline__ float rcp_f(float x) { return __builtin_amdgcn_rcpf(x); }

__device__ __forceinline__ float fdot2(h2 a, h2 b, float c) {
  return __builtin_amdgcn_fdot2(a, b, c, false);
}
__device__ __forceinline__ h2 mk2(f16 a, f16 b) { h2 v; v[0] = a; v[1] = b; return v; }

__device__ __forceinline__ float fast_tanh(float x) {
  x = fminf(fmaxf(x, -12.f), 12.f);
  float e = __expf(2.f * x);
  return (e - 1.f) * rcp_f(e + 1.f);
}
__device__ __forceinline__ float fast_sig(float x) {
  x = fminf(fmaxf(x, -30.f), 30.f);
  return rcp_f(1.f + __expf(-x));
}

// LDS-only barrier: drains lgkmcnt (DS ops) but NOT vmcnt, so global
// prefetch loads stay in flight across the barrier. Only LDS carries
// cross-wave data in the step loop, so this is sufficient.
__device__ __forceinline__ void bar_lds() {
  asm volatile("s_waitcnt lgkmcnt(0)" ::: "memory");
  __builtin_amdgcn_s_barrier();
  asm volatile("" ::: "memory");
}

// ---- pack Wa1 h+c parts fp32 -> fp16 single u-stream ----
// wsU[(it*512 + L)*8 + j] = Wa1[L>>1][(it>>4)*256 + (L&1)*128 + (it&15)*8 + j]
// it 0..15: h-cols; it 16..31: c-cols. 256 KB.
__global__ void pack_wsU(const float* __restrict__ Wa1, f16* __restrict__ wsU) {
  int tid = blockIdx.x * 256 + threadIdx.x;  // 64 blocks
  int it = tid >> 9, L = tid & 511;
  int kL = L >> 1, g2 = L & 1;
  const float* src = Wa1 + (size_t)kL * 768 + (it >> 4) * 256 + g2 * 128 + (it & 15) * 8;
  f16* dst = wsU + (size_t)tid * 8;
#pragma unroll
  for (int j = 0; j < 8; ++j) dst[j] = (f16)src[j];
}

// ---- pack Whh fp32 -> fp16, per-cell 4-gate contiguous stream ----
// wsH[((i*256 + kk)*4 + g)*8 + j] = Whh[(g*256+kk)*256 + i*8 + j]
// Per k-chunk i, a lane owning cell kk loads its 4 gate-weights from 64
// contiguous bytes. 512 KB.
__global__ void pack_wsH(const float* __restrict__ Whh, f16* __restrict__ wsH) {
  int tid = blockIdx.x * 256 + threadIdx.x;  // 128 blocks -> 32768
  int i = tid >> 10, kk = (tid >> 2) & 255, g = tid & 3;
  const float* src = Whh + (size_t)(g * 256 + kk) * 256 + i * 8;
  f16* dst = wsH + (size_t)tid * 8;
#pragma unroll
  for (int j = 0; j < 8; ++j) dst[j] = (f16)src[j];
}

// 256 blocks x 512 threads, 1 block/CU (LDS-limited; 512-thread WG -> hard
// 128-VGPR budget, launch_bounds/waves_per_eu requests for 256 are IGNORED).
// Round-11: rounds 8-10 spilled (~16GB scratch W+R) because FULL unrolls of
// the A1(32-iter) and fused(16-iter) loops let the scheduler hoist all
// independent loads -> live ranges blew past 128 regardless of array sizes.
// This round returns to round-0's scheduling discipline (unroll 4 / unroll 1
// + macro bodies + named ping-pong regs, ~100 VGPR proven) and keeps only
// the register-neutral algorithmic wins:
//   (1) split-K Whh: lane pairs split the 256-dot (g2 = lo/hi 16 chunks);
//       each lane loads 4-gate-contiguous 64B/chunk (half the VMEM issue
//       and L2 traffic of the dominant stream), computes both batches,
//       pair-combines via shfl_xor(1).
//   (2) tE1 conflict-free geometry (272-half rows; conflicts 1.34e8->5.1e7).
//   (3) bar_lds: lgkmcnt-only barrier keeps prefetch loads in flight.
__global__ __attribute__((amdgpu_flat_work_group_size(512, 512)))
void decoder_kernel(
    const float* __restrict__ enc,    // [512][127][256]
    const float* __restrict__ yhist,  // [512][127]
    const float* __restrict__ Wa1,    // [256][768] (prologue only)
    const float* __restrict__ ba1,    // [256]
    const float* __restrict__ Wa2,    // [256]
    const float* __restrict__ ba2,    // [1]
    const float* __restrict__ Wih,    // [1024]
    const float* __restrict__ bih,    // [1024]
    const float* __restrict__ bhh,    // [1024]
    const float* __restrict__ Wfc,    // [257]
    const float* __restrict__ bfc,    // [1]
    const float* __restrict__ Wfcf,   // [512]
    const float* __restrict__ bfcf,   // [1]
    const f16* __restrict__ wsU,      // packed Wa1 h|c [32][512][8]
    const f16* __restrict__ wsH,      // packed Whh [32][256][4][8]
    float* __restrict__ outp)         // [512] out ++ [512][127][127] weight
{
  // tE1 flat: b*34592 + j*272 + g*68 + e (halves).
  __shared__ __align__(16) f16 tE1[2 * 34592];
  __shared__ __align__(16) f16 hch[2][4][136];      // h (chunks 0,1) | c (2,3) fp16
  __shared__ __align__(16) float s_arr[2][4][68];   // s = tanh(u+b1)
  __shared__ __align__(16) float score_s[2][128];
  __shared__ __align__(16) float p_s[2][128];       // e . Wfc[0:256]
  __shared__ __align__(16) float q_s[2][128];       // e . Wfcf[256:512]
  __shared__ __align__(16) f16 est[8][288];         // prologue staging
  __shared__ __align__(16) float w2_lds[256];
  __shared__ __align__(16) float yh_s[2][128];
  __shared__ float ctxq_s[2], red2[16];

  const int L = threadIdx.x;   // 0..511
  const int b0 = blockIdx.x * 2;
  const int kL = L >> 1;       // u-output index 0..255
  const int g2 = L & 1;        // col-half / K-half selector
  const int kk2 = L >> 1;      // owned LSTM cell
  const int bbE = L & 1;       // owned batch (cell state)
  const int g_u = L & 3;

  // ---------------- init ----------------
  for (int i = L; i < 1088; i += 512) ((f16*)hch)[i] = (f16)0.f;
  if (L < 256) {
    w2_lds[L] = Wa2[L];
    int bb = L >> 7, tt = L & 127;
    if (tt < T127) yh_s[bb][tt] = yhist[(size_t)(b0 + bb) * T127 + tt];
  }
  float c_reg = 0.f;  // fp32 cell state for (bbE, kk2)

  // ---------------- prologue: tE1 = tanh(e.W1e), p, q ----------------
  {
    h2 we1[64];  // W1e[kL][g2*128 .. +128]
    {
      const float4* wrow = (const float4*)(Wa1 + (size_t)kL * 768 + 512 + g2 * 128);
#pragma unroll
      for (int i = 0; i < 32; ++i) {
        float4 w = wrow[i];
        we1[2 * i]     = mk2((f16)w.x, (f16)w.y);
        we1[2 * i + 1] = mk2((f16)w.z, (f16)w.w);
      }
    }
    const int prow = L >> 6;      // wave id = staged row 0..7
    const int lm = L & 63;
    const int sg = lm >> 4;       // staging chunk 0..3 (72-elem stride)
    const int si = (lm * 4) & 63;

#pragma unroll 1
    for (int tt = 0; tt < 32; ++tt) {
      __syncthreads();
      {  // stage 8 (b,j) rows as fp16: row = bbs*4 + j4, j = tt*4+j4
        int bbs = prow >> 2, j4 = prow & 3, j = tt * 4 + j4;
        float4 v = make_float4(0.f, 0.f, 0.f, 0.f);
        if (j < T127)
          v = *(const float4*)(enc + (((size_t)(b0 + bbs)) * T127 + j) * 256 + lm * 4);
        h4 hv; hv[0] = (f16)v.x; hv[1] = (f16)v.y; hv[2] = (f16)v.z; hv[3] = (f16)v.w;
        *(h4*)(&est[prow][0] + sg * 72 + si) = hv;
      }
      __syncthreads();
#pragma unroll 1
      for (int P = 0; P < 8; ++P) {
        int bbs = P >> 2, j4 = P & 3, j = tt * 4 + j4;
        const h8* ep = (const h8*)(&est[P][0] + (2 * g2) * 72);
        const h8* ep2 = (const h8*)(&est[P][0] + (2 * g2 + 1) * 72);
        float a0 = 0.f, a1 = 0.f;
#pragma unroll
        for (int r = 0; r < 8; ++r) {
          h8 e8 = ep[r];
          a0 = fdot2(we1[4 * r + 0], mk2(e8[0], e8[1]), a0);
          a1 = fdot2(we1[4 * r + 1], mk2(e8[2], e8[3]), a1);
          a0 = fdot2(we1[4 * r + 2], mk2(e8[4], e8[5]), a0);
          a1 = fdot2(we1[4 * r + 3], mk2(e8[6], e8[7]), a1);
        }
#pragma unroll
        for (int r = 0; r < 8; ++r) {
          h8 e8 = ep2[r];
          a0 = fdot2(we1[32 + 4 * r + 0], mk2(e8[0], e8[1]), a0);
          a1 = fdot2(we1[32 + 4 * r + 1], mk2(e8[2], e8[3]), a1);
          a0 = fdot2(we1[32 + 4 * r + 2], mk2(e8[4], e8[5]), a0);
          a1 = fdot2(we1[32 + 4 * r + 3], mk2(e8[6], e8[7]), a1);
        }
        float acc = a0 + a1;
        acc += __shfl_xor(acc, 1, 64);
        if (g2 == 0 && j < T127)
          tE1[bbs * 34592 + j * 272 + (kL >> 6) * 68 + (kL & 63)] = (f16)fast_tanh(acc);
      }
      {  // p, q for this wave's staged row
        int bbs = prow >> 2, j4 = prow & 3, j = tt * 4 + j4;
        float4 wp4 = *(const float4*)(Wfc + lm * 4);
        float4 wq4 = *(const float4*)(Wfcf + 256 + lm * 4);
        h4 ev = *(const h4*)(&est[prow][0] + sg * 72 + si);
        float pacc = (float)ev[0] * wp4.x + (float)ev[1] * wp4.y + (float)ev[2] * wp4.z + (float)ev[3] * wp4.w;
        float qacc = (float)ev[0] * wq4.x + (float)ev[1] * wq4.y + (float)ev[2] * wq4.z + (float)ev[3] * wq4.w;
#pragma unroll
        for (int s = 32; s; s >>= 1) {
          pacc += __shfl_xor(pacc, s, 64);
          qacc += __shfl_xor(qacc, s, 64);
        }
        if (lm == 0 && j < T127) { p_s[bbs][j] = pacc; q_s[bbs][j] = qacc; }
      }
    }
  }
  __syncthreads();

  // ---------------- persistent per-lane constants ----------------
  const float b1k = ba1[kL];
  const float wih0 = Wih[kk2];            // gate i row
  const float wih1 = Wih[256 + kk2];      // f
  const float wih2 = Wih[512 + kk2];      // g
  const float wih3 = Wih[768 + kk2];      // o
  const float bia0 = bih[kk2] + bhh[kk2];
  const float bia1 = bih[256 + kk2] + bhh[256 + kk2];
  const float bia2 = bih[512 + kk2] + bhh[512 + kk2];
  const float bia3 = bih[768 + kk2] + bhh[768 + kk2];
  const float ba2v = ba2[0];
  const float wfcy = Wfc[256];
  const float bfc0 = bfc[0];
  const float wfcf_k = Wfcf[kk2];

  // ---------------- stream / score pointers ----------------
  const h8* wp = (const h8*)wsU + L;                                 // u-stream
  const h8* wb = (const h8*)wsH + ((size_t)g2 * 16 * 256 + kk2) * 4; // Whh stream
  const f16* hxb = (const f16*)hch + g2 * 136;  // own K-half chunk base (batch0)

  const int prA = L >> 2;                  // score row, first pass (0..127)
  const int bbA = prA & 1, jA = prA >> 1;
  const int prB = prA + 128;               // second pass
  const int prC = prB < 254 ? prB : 253;
  const int bbB2 = prC & 1, jB2 = prC >> 1;
  const h4* tpA = (const h4*)(tE1 + bbA * 34592 + jA * 272 + g_u * 68);
  const h4* tpB = (const h4*)(tE1 + bbB2 * 34592 + jB2 * 272 + g_u * 68);
  const float4* spA = (const float4*)&s_arr[bbA][g_u][0];
  const float4* spB = (const float4*)&s_arr[bbB2][g_u][0];
  const float4* w2p = (const float4*)&w2_lds[g_u * 64];

  // ---------------- 127 sequential steps ----------------
#pragma unroll 1
  for (int t = 0; t < T127; ++t) {
    // ---- Phase A1: u = Wa1.[h;c], 4-deep named rotation (round-0 form) ----
    float u0a = 0.f, u0b = 0.f, u1a = 0.f, u1b = 0.f;
    {
      h8 a0 = wp[0], a1 = wp[512], a2 = wp[1024], a3 = wp[1536];
#pragma unroll 4
      for (int it = 0; it < 32; ++it) {
        h8 nxt = wp[((it + 4) & 31) * 512];
        const f16* hp = hxb + (it >> 4) * 272 + (it & 15) * 8;
        h8 x = *(const h8*)hp;           // batch 0
        h8 y = *(const h8*)(hp + 544);   // batch 1
        u0a = fdot2(mk2(a0[0], a0[1]), mk2(x[0], x[1]), u0a);
        u0b = fdot2(mk2(a0[2], a0[3]), mk2(x[2], x[3]), u0b);
        u0a = fdot2(mk2(a0[4], a0[5]), mk2(x[4], x[5]), u0a);
        u0b = fdot2(mk2(a0[6], a0[7]), mk2(x[6], x[7]), u0b);
        u1a = fdot2(mk2(a0[0], a0[1]), mk2(y[0], y[1]), u1a);
        u1b = fdot2(mk2(a0[2], a0[3]), mk2(y[2], y[3]), u1b);
        u1a = fdot2(mk2(a0[4], a0[5]), mk2(y[4], y[5]), u1a);
        u1b = fdot2(mk2(a0[6], a0[7]), mk2(y[6], y[7]), u1b);
        a0 = a1; a1 = a2; a2 = a3; a3 = nxt;
      }
    }
    {
      float u0 = u0a + u0b, u1 = u1a + u1b;
      u0 += __shfl_xor(u0, 1, 64);
      u1 += __shfl_xor(u1, 1, 64);
      if (g2 == 0) s_arr[0][kL >> 6][kL & 63] = fast_tanh(u0 + b1k);
      else         s_arr[1][kL >> 6][kL & 63] = fast_tanh(u1 + b1k);
    }
    // fused W prefetch (chunks 0,1), issued BEFORE the barrier: latency
    // overlaps the barrier wait (bar_lds does not drain vmcnt).
    h8 A0 = wb[0], A1r = wb[1], A2 = wb[2], A3 = wb[3];
    h8 B0 = wb[1024], B1 = wb[1025], B2 = wb[1026], B3 = wb[1027];
    bar_lds();  // #1: s_arr visible

    // ---- Fused: split-K Whh (4 gates x 2 batches) + attn scores ----
    float ghA0 = 0.f, ghA1 = 0.f, ghA2 = 0.f, ghA3 = 0.f;  // batch 0, own K-half
    float ghB0 = 0.f, ghB1 = 0.f, ghB2 = 0.f, ghB3 = 0.f;  // batch 1, own K-half
    float accA0 = 0.f, accA1 = 0.f, accB0 = 0.f, accB1 = 0.f;

#define GH8(acc, w, v)                                   \
    acc = fdot2(mk2(w[0], w[1]), mk2(v[0], v[1]), acc);  \
    acc = fdot2(mk2(w[2], w[3]), mk2(v[2], v[3]), acc);  \
    acc = fdot2(mk2(w[4], w[5]), mk2(v[4], v[5]), acc);  \
    acc = fdot2(mk2(w[6], w[7]), mk2(v[6], v[7]), acc);

#define FBODY(C0, C1, C2, C3, II)                                              \
    {                                                                          \
      int ipn = ((II) + 2) & 15;                                               \
      h8 T0 = wb[ipn * 1024 + 0], T1 = wb[ipn * 1024 + 1];                     \
      h8 T2 = wb[ipn * 1024 + 2], T3 = wb[ipn * 1024 + 3];                     \
      h8 x = *(const h8*)(hxb + (II) * 8);          /* batch 0 */              \
      h8 y = *(const h8*)(hxb + 544 + (II) * 8);    /* batch 1 */              \
      GH8(ghA0, C0, x)  GH8(ghB0, C0, y)                                       \
      GH8(ghA1, C1, x)  GH8(ghB1, C1, y)                                       \
      GH8(ghA2, C2, x)  GH8(ghB2, C2, y)                                       \
      GH8(ghA3, C3, x)  GH8(ghB3, C3, y)                                       \
      {                                                                        \
        float4 wv = w2p[(II)];                                                 \
        h4 tv = tpA[(II)];                                                     \
        float4 sv = spA[(II)];                                                 \
        float t0 = (float)tv[0], t1 = (float)tv[1];                            \
        float t2 = (float)tv[2], t3 = (float)tv[3];                            \
        accA0 = fmaf(wv.x * (sv.x + t0), rcp_f(fmaf(sv.x, t0, 1.f)), accA0);   \
        accA1 = fmaf(wv.y * (sv.y + t1), rcp_f(fmaf(sv.y, t1, 1.f)), accA1);   \
        accA0 = fmaf(wv.z * (sv.z + t2), rcp_f(fmaf(sv.z, t2, 1.f)), accA0);   \
        accA1 = fmaf(wv.w * (sv.w + t3), rcp_f(fmaf(sv.w, t3, 1.f)), accA1);   \
        h4 tw = tpB[(II)];                                                     \
        float4 sw = spB[(II)];                                                 \
        float r0 = (float)tw[0], r1 = (float)tw[1];                            \
        float r2 = (float)tw[2], r3 = (float)tw[3];                            \
        accB0 = fmaf(wv.x * (sw.x + r0), rcp_f(fmaf(sw.x, r0, 1.f)), accB0);   \
        accB1 = fmaf(wv.y * (sw.y + r1), rcp_f(fmaf(sw.y, r1, 1.f)), accB1);   \
        accB0 = fmaf(wv.z * (sw.z + r2), rcp_f(fmaf(sw.z, r2, 1.f)), accB0);   \
        accB1 = fmaf(wv.w * (sw.w + r3), rcp_f(fmaf(sw.w, r3, 1.f)), accB1);   \
      }                                                                        \
      C0 = T0; C1 = T1; C2 = T2; C3 = T3;                                      \
    }

#pragma unroll 1
    for (int ih = 0; ih < 8; ++ih) {
      FBODY(A0, A1r, A2, A3, 2 * ih)
      FBODY(B0, B1, B2, B3, 2 * ih + 1)
    }
#undef FBODY
#undef GH8
    {
      float accA = accA0 + accA1;
      accA += __shfl_xor(accA, 1, 64);
      accA += __shfl_xor(accA, 2, 64);
      if (g_u == 0) score_s[bbA][jA] = accA + ba2v;
      float accB = accB0 + accB1;
      accB += __shfl_xor(accB, 1, 64);
      accB += __shfl_xor(accB, 2, 64);
      if (g_u == 0 && prB < 254) score_s[bbB2][jB2] = accB + ba2v;
    }
    // pair-combine K-halves: lane's own batch is bbE==g2; partner holds
    // the other K-half of my batch in its same-named accumulator.
    float gh0, gh1, gh2, gh3;
    {
      float s0 = g2 ? ghA0 : ghB0, k0 = g2 ? ghB0 : ghA0;
      float s1 = g2 ? ghA1 : ghB1, k1 = g2 ? ghB1 : ghA1;
      float s2 = g2 ? ghA2 : ghB2, k2v = g2 ? ghB2 : ghA2;
      float s3 = g2 ? ghA3 : ghB3, k3 = g2 ? ghB3 : ghA3;
      gh0 = k0 + __shfl_xor(s0, 1, 64);
      gh1 = k1 + __shfl_xor(s1, 1, 64);
      gh2 = k2v + __shfl_xor(s2, 1, 64);
      gh3 = k3 + __shfl_xor(s3, 1, 64);
    }
    bar_lds();  // #2: score_s visible

    // ---- Phase C: redundant per-wave softmax, interleaved reductions ----
    float ytil0, ytil1;
    float ra, rb;
    {
      const int ln = L & 63;
      const int wv = L >> 6;
      float e0a = __expf(score_s[0][ln]);
      float e1a = (ln < 63) ? __expf(score_s[0][64 + ln]) : 0.f;
      float e0b = __expf(score_s[1][ln]);
      float e1b = (ln < 63) ? __expf(score_s[1][64 + ln]) : 0.f;
      float sa = e0a + e1a, sb = e0b + e1b;
      float cwa = e0a * p_s[0][ln] + ((ln < 63) ? e1a * p_s[0][64 + ln] : 0.f);
      float cwb = e0b * p_s[1][ln] + ((ln < 63) ? e1b * p_s[1][64 + ln] : 0.f);
#pragma unroll
      for (int s = 32; s; s >>= 1) {
        sa += __shfl_xor(sa, s, 64);
        sb += __shfl_xor(sb, s, 64);
        cwa += __shfl_xor(cwa, s, 64);
        cwb += __shfl_xor(cwb, s, 64);
      }
      ra = rcp_f(sa); rb = rcp_f(sb);
      if (wv == 0) {
        float* wout = outp + 512 + ((size_t)b0 * T127 + t) * T127;
        wout[ln] = e0a * ra;
        if (ln < 63) wout[64 + ln] = e1a * ra;
      } else if (wv == 1) {
        float* wout = outp + 512 + ((size_t)(b0 + 1) * T127 + t) * T127;
        wout[ln] = e0b * rb;
        if (ln < 63) wout[64 + ln] = e1b * rb;
      }
      ytil0 = cwa * ra + wfcy * yh_s[0][t] + bfc0;
      ytil1 = cwb * rb + wfcy * yh_s[1][t] + bfc0;
      if (t == T127 - 1) {
        float cqa = e0a * q_s[0][ln] + ((ln < 63) ? e1a * q_s[0][64 + ln] : 0.f);
        float cqb = e0b * q_s[1][ln] + ((ln < 63) ? e1b * q_s[1][64 + ln] : 0.f);
#pragma unroll
        for (int s = 32; s; s >>= 1) {
          cqa += __shfl_xor(cqa, s, 64);
          cqb += __shfl_xor(cqb, s, 64);
        }
        if (L == 0) { ctxq_s[0] = cqa * ra; ctxq_s[1] = cqb * rb; }
      }
    }

    // ---- Phase D+E fused: gates + cell update, all in-lane ----
    {
      float yt = bbE ? ytil1 : ytil0;
      float g_i = gh0 + wih0 * yt + bia0;
      float g_f = gh1 + wih1 * yt + bia1;
      float g_g = gh2 + wih2 * yt + bia2;
      float g_o = gh3 + wih3 * yt + bia3;
      float ai = fast_sig(g_i);
      float af = fast_sig(g_f);
      float ag = fast_tanh(g_g);
      float ao = fast_sig(g_o);
      float cn = af * c_reg + ai * ag;
      float hn = ao * fast_tanh(cn);
      c_reg = cn;
      hch[bbE][kk2 >> 7][kk2 & 127] = (f16)hn;
      hch[bbE][2 + (kk2 >> 7)][kk2 & 127] = (f16)cn;
      if (t == T127 - 1) {
        float po = wfcf_k * hn;
        po += __shfl_xor(po, 32, 64);
        po += __shfl_xor(po, 16, 64);
        po += __shfl_xor(po, 8, 64);
        po += __shfl_xor(po, 4, 64);
        po += __shfl_xor(po, 2, 64);
        if ((L & 63) < 2) red2[(L >> 6) * 2 + (L & 1)] = po;
      }
    }
    bar_lds();  // #3: hch (+ red2/ctxq on last step) visible
  }

  // ---------------- final: out = Wfcf[0:256].h + ctx.Wfcf[256:512] + b ----------------
  if (L < 2) {
    float o = ctxq_s[L] + bfcf[0];
#pragma unroll
    for (int w = 0; w < 8; ++w) o += red2[w * 2 + L];
    outp[b0 + L] = o;
  }
}

extern "C" void kernel_launch(void* const* d_in, const int* in_sizes, int n_in,
                              void* d_out, int out_size, void* d_ws, size_t ws_size,
                              hipStream_t stream) {
  (void)in_sizes; (void)n_in; (void)out_size; (void)ws_size;
  f16* wsU = (f16*)d_ws;            // 32*512*8 = 131072 halves (256 KiB)
  f16* wsH = wsU + 131072;          // 32*256*4*8 = 262144 halves (512 KiB)
  pack_wsU<<<64, 256, 0, stream>>>((const float*)d_in[2], wsU);
  pack_wsH<<<128, 256, 0, stream>>>((const float*)d_in[7], wsH);
  decoder_kernel<<<256, 512, 0, stream>>>(
      (const float*)d_in[0], (const float*)d_in[1], (const float*)d_in[2],
      (const float*)d_in[3], (const float*)d_in[4], (const float*)d_in[5],
      (const float*)d_in[6], (const float*)d_in[8], (const float*)d_in[9],
      (const float*)d_in[10], (const float*)d_in[11], (const float*)d_in[12],
      (const float*)d_in[13], wsU, wsH, (float*)d_out);
}

// Round 5
// 1623.562 us; speedup vs baseline: 9.9983x; 1.0077x over previous
//
#include <hip/hip_runtime.h>

typedef _Float16 f16;
typedef _Float16 h2 __attribute__((ext_vector_type(2)));
typedef _Float16 h4 __attribute__((ext_vector_type(4)));
typedef _Float16 h8 __attribute__((ext_vector_type(8)));

#define T127 127

// Extract aligned h2 subregister i from an h8 (even-pair): guaranteed
// subregister no-op, unlike building h2 from scalar extracts.
#define H2S(v, i) __builtin_shufflevector(v, v, 2 * (i), 2 * (i) + 1)

__device__ __forceinline__ float rcp_f(float x) { return __builtin_amdgcn_rcpf(x); }

__device__ __forceinline__ float fdot2(h2 a, h2 b, float c) {
  return __builtin_amdgcn_fdot2(a, b, c, false);
}
__device__ __forceinline__ h2 mk2(f16 a, f16 b) { h2 v; v[0] = a; v[1] = b; return v; }

__device__ __forceinline__ float fast_sig(float x) {
  x = fminf(fmaxf(x, -30.f), 30.f);
  return rcp_f(1.f + __expf(-x));
}
__device__ __forceinline__ float fast_tanh(float x) {
  x = fminf(fmaxf(x, -12.f), 12.f);
  float e = __expf(2.f * x);
  return (e - 1.f) * rcp_f(e + 1.f);
}

// LDS-only barrier: drains lgkmcnt (DS ops) but NOT vmcnt, so global
// prefetch loads stay in flight across the barrier.
__device__ __forceinline__ void bar_lds() {
  asm volatile("s_waitcnt lgkmcnt(0)" ::: "memory");
  __builtin_amdgcn_s_barrier();
  asm volatile("" ::: "memory");
}

// ---- pack Wa1 h+c parts fp32 -> fp16 single u-stream ----
__global__ void pack_wsU(const float* __restrict__ Wa1, f16* __restrict__ wsU) {
  int tid = blockIdx.x * 256 + threadIdx.x;  // 64 blocks
  int it = tid >> 9, L = tid & 511;
  int kL = L >> 1, g2 = L & 1;
  const float* src = Wa1 + (size_t)kL * 768 + (it >> 4) * 256 + g2 * 128 + (it & 15) * 8;
  f16* dst = wsU + (size_t)tid * 8;
#pragma unroll
  for (int j = 0; j < 8; ++j) dst[j] = (f16)src[j];
}

// ---- pack Whh fp32 -> fp16, per-cell 4-gate contiguous stream ----
__global__ void pack_wsH(const float* __restrict__ Whh, f16* __restrict__ wsH) {
  int tid = blockIdx.x * 256 + threadIdx.x;  // 128 blocks -> 32768
  int i = tid >> 10, kk = (tid >> 2) & 255, g = tid & 3;
  const float* src = Whh + (size_t)(g * 256 + kk) * 256 + i * 8;
  f16* dst = wsH + (size_t)tid * 8;
#pragma unroll
  for (int j = 0; j < 8; ++j) dst[j] = (f16)src[j];
}

// 256 blocks x 512 threads, 1 block/CU (LDS-limited; 512-thread WG -> hard
// 128-VGPR budget; keep the round-4 unroll discipline that fits it).
// Round-12 (on top of round-4's 1636us):
//   (1) all hot-loop mk2(v[i],v[i+1]) -> __builtin_shufflevector aligned
//       subregister extraction (H2S): removes any v_pack/v_perm repack ops
//       the compiler was emitting per fdot2 operand (768 fdot2/step).
//   (2) score in exp-space: s_arr/tE1 store E=exp(2*arg) (tE1 clamped to
//       e^+-9, fp16-normal range); w2*tanh(s+t) = w2 - 2*w2/(Es*Et+1),
//       with per-row Sum(w2) folded in as per-lane seed W2q. Inner score
//       element: cvt+fma+rcp+fma (was cvt+add+mul+fma+rcp+fma).
__global__ __attribute__((amdgpu_flat_work_group_size(512, 512)))
void decoder_kernel(
    const float* __restrict__ enc,    // [512][127][256]
    const float* __restrict__ yhist,  // [512][127]
    const float* __restrict__ Wa1,    // [256][768] (prologue only)
    const float* __restrict__ ba1,    // [256]
    const float* __restrict__ Wa2,    // [256]
    const float* __restrict__ ba2,    // [1]
    const float* __restrict__ Wih,    // [1024]
    const float* __restrict__ bih,    // [1024]
    const float* __restrict__ bhh,    // [1024]
    const float* __restrict__ Wfc,    // [257]
    const float* __restrict__ bfc,    // [1]
    const float* __restrict__ Wfcf,   // [512]
    const float* __restrict__ bfcf,   // [1]
    const f16* __restrict__ wsU,      // packed Wa1 h|c [32][512][8]
    const f16* __restrict__ wsH,      // packed Whh [32][256][4][8]
    float* __restrict__ outp)         // [512] out ++ [512][127][127] weight
{
  // tE1 flat: b*34592 + j*272 + g*68 + e (halves). Stores exp(2*(e.W1e))
  // clamped to e^+-9. 272-half rows + 34592-half batch stride ->
  // conflict-free b64 reads.
  __shared__ __align__(16) f16 tE1[2 * 34592];
  __shared__ __align__(16) f16 hch[2][4][136];      // h (chunks 0,1) | c (2,3) fp16
  __shared__ __align__(16) float s_arr[2][4][68];   // Es = exp(2*(u+b1))
  __shared__ __align__(16) float score_s[2][128];
  __shared__ __align__(16) float p_s[2][128];       // e . Wfc[0:256]
  __shared__ __align__(16) float q_s[2][128];       // e . Wfcf[256:512]
  __shared__ __align__(16) f16 est[8][288];         // prologue staging
  __shared__ __align__(16) float w2_lds[256];
  __shared__ __align__(16) float yh_s[2][128];
  __shared__ float ctxq_s[2], red2[16];

  const int L = threadIdx.x;   // 0..511
  const int b0 = blockIdx.x * 2;
  const int kL = L >> 1;       // u-output index 0..255
  const int g2 = L & 1;        // col-half / K-half selector
  const int kk2 = L >> 1;      // owned LSTM cell
  const int bbE = L & 1;       // owned batch (cell state)
  const int g_u = L & 3;

  // ---------------- init ----------------
  for (int i = L; i < 1088; i += 512) ((f16*)hch)[i] = (f16)0.f;
  if (L < 256) {
    w2_lds[L] = Wa2[L];
    int bb = L >> 7, tt = L & 127;
    if (tt < T127) yh_s[bb][tt] = yhist[(size_t)(b0 + bb) * T127 + tt];
  }
  float c_reg = 0.f;  // fp32 cell state for (bbE, kk2)

  // ---------------- prologue: tE1 = exp(2*e.W1e), p, q ----------------
  {
    h2 we1[64];  // W1e[kL][g2*128 .. +128]
    {
      const float4* wrow = (const float4*)(Wa1 + (size_t)kL * 768 + 512 + g2 * 128);
#pragma unroll
      for (int i = 0; i < 32; ++i) {
        float4 w = wrow[i];
        we1[2 * i]     = mk2((f16)w.x, (f16)w.y);
        we1[2 * i + 1] = mk2((f16)w.z, (f16)w.w);
      }
    }
    const int prow = L >> 6;      // wave id = staged row 0..7
    const int lm = L & 63;
    const int sg = lm >> 4;       // staging chunk 0..3 (72-elem stride)
    const int si = (lm * 4) & 63;

#pragma unroll 1
    for (int tt = 0; tt < 32; ++tt) {
      __syncthreads();
      {  // stage 8 (b,j) rows as fp16: row = bbs*4 + j4, j = tt*4+j4
        int bbs = prow >> 2, j4 = prow & 3, j = tt * 4 + j4;
        float4 v = make_float4(0.f, 0.f, 0.f, 0.f);
        if (j < T127)
          v = *(const float4*)(enc + (((size_t)(b0 + bbs)) * T127 + j) * 256 + lm * 4);
        h4 hv; hv[0] = (f16)v.x; hv[1] = (f16)v.y; hv[2] = (f16)v.z; hv[3] = (f16)v.w;
        *(h4*)(&est[prow][0] + sg * 72 + si) = hv;
      }
      __syncthreads();
#pragma unroll 1
      for (int P = 0; P < 8; ++P) {
        int bbs = P >> 2, j4 = P & 3, j = tt * 4 + j4;
        const h8* ep = (const h8*)(&est[P][0] + (2 * g2) * 72);
        const h8* ep2 = (const h8*)(&est[P][0] + (2 * g2 + 1) * 72);
        float a0 = 0.f, a1 = 0.f;
#pragma unroll
        for (int r = 0; r < 8; ++r) {
          h8 e8 = ep[r];
          a0 = fdot2(we1[4 * r + 0], H2S(e8, 0), a0);
          a1 = fdot2(we1[4 * r + 1], H2S(e8, 1), a1);
          a0 = fdot2(we1[4 * r + 2], H2S(e8, 2), a0);
          a1 = fdot2(we1[4 * r + 3], H2S(e8, 3), a1);
        }
#pragma unroll
        for (int r = 0; r < 8; ++r) {
          h8 e8 = ep2[r];
          a0 = fdot2(we1[32 + 4 * r + 0], H2S(e8, 0), a0);
          a1 = fdot2(we1[32 + 4 * r + 1], H2S(e8, 1), a1);
          a0 = fdot2(we1[32 + 4 * r + 2], H2S(e8, 2), a0);
          a1 = fdot2(we1[32 + 4 * r + 3], H2S(e8, 3), a1);
        }
        float acc = a0 + a1;
        acc += __shfl_xor(acc, 1, 64);
        if (g2 == 0 && j < T127) {
          float z = fminf(fmaxf(2.f * acc, -9.f), 9.f);
          tE1[bbs * 34592 + j * 272 + (kL >> 6) * 68 + (kL & 63)] = (f16)__expf(z);
        }
      }
      {  // p, q for this wave's staged row
        int bbs = prow >> 2, j4 = prow & 3, j = tt * 4 + j4;
        float4 wp4 = *(const float4*)(Wfc + lm * 4);
        float4 wq4 = *(const float4*)(Wfcf + 256 + lm * 4);
        h4 ev = *(const h4*)(&est[prow][0] + sg * 72 + si);
        float pacc = (float)ev[0] * wp4.x + (float)ev[1] * wp4.y + (float)ev[2] * wp4.z + (float)ev[3] * wp4.w;
        float qacc = (float)ev[0] * wq4.x + (float)ev[1] * wq4.y + (float)ev[2] * wq4.z + (float)ev[3] * wq4.w;
#pragma unroll
        for (int s = 32; s; s >>= 1) {
          pacc += __shfl_xor(pacc, s, 64);
          qacc += __shfl_xor(qacc, s, 64);
        }
        if (lm == 0 && j < T127) { p_s[bbs][j] = pacc; q_s[bbs][j] = qacc; }
      }
    }
  }
  __syncthreads();

  // ---------------- persistent per-lane constants ----------------
  const float b1k = ba1[kL];
  const float wih0 = Wih[kk2];            // gate i row
  const float wih1 = Wih[256 + kk2];      // f
  const float wih2 = Wih[512 + kk2];      // g
  const float wih3 = Wih[768 + kk2];      // o
  const float bia0 = bih[kk2] + bhh[kk2];
  const float bia1 = bih[256 + kk2] + bhh[256 + kk2];
  const float bia2 = bih[512 + kk2] + bhh[512 + kk2];
  const float bia3 = bih[768 + kk2] + bhh[768 + kk2];
  const float ba2v = ba2[0];
  const float wfcy = Wfc[256];
  const float bfc0 = bfc[0];
  const float wfcf_k = Wfcf[kk2];

  // ---------------- stream / score pointers ----------------
  const h8* wp = (const h8*)wsU + L;                                 // u-stream
  const h8* wb = (const h8*)wsH + ((size_t)g2 * 16 * 256 + kk2) * 4; // Whh stream
  const f16* hxb = (const f16*)hch + g2 * 136;  // own K-half chunk base (batch0)

  const int prA = L >> 2;                  // score row, first pass (0..127)
  const int bbA = prA & 1, jA = prA >> 1;
  const int prB = prA + 128;               // second pass
  const int prC = prB < 254 ? prB : 253;
  const int bbB2 = prC & 1, jB2 = prC >> 1;
  const h4* tpA = (const h4*)(tE1 + bbA * 34592 + jA * 272 + g_u * 68);
  const h4* tpB = (const h4*)(tE1 + bbB2 * 34592 + jB2 * 272 + g_u * 68);
  const float4* spA = (const float4*)&s_arr[bbA][g_u][0];
  const float4* spB = (const float4*)&s_arr[bbB2][g_u][0];
  const float4* w2p = (const float4*)&w2_lds[g_u * 64];

  // per-lane quarter-sum of w2: seed for the exp-space score
  // (score = Sum_q(W2q - 2*acc_q) + ba2; the 4-lane shfl combine sums quarters)
  float W2q = 0.f;
#pragma unroll
  for (int i = 0; i < 16; ++i) {
    float4 v = w2p[i];
    W2q += v.x + v.y + v.z + v.w;
  }

  // ---------------- 127 sequential steps ----------------
#pragma unroll 1
  for (int t = 0; t < T127; ++t) {
    // ---- Phase A1: u = Wa1.[h;c], 4-deep named rotation ----
    float u0a = 0.f, u0b = 0.f, u1a = 0.f, u1b = 0.f;
    {
      h8 a0 = wp[0], a1 = wp[512], a2 = wp[1024], a3 = wp[1536];
#pragma unroll 4
      for (int it = 0; it < 32; ++it) {
        h8 nxt = wp[((it + 4) & 31) * 512];
        const f16* hp = hxb + (it >> 4) * 272 + (it & 15) * 8;
        h8 x = *(const h8*)hp;           // batch 0
        h8 y = *(const h8*)(hp + 544);   // batch 1
        u0a = fdot2(H2S(a0, 0), H2S(x, 0), u0a);
        u0b = fdot2(H2S(a0, 1), H2S(x, 1), u0b);
        u0a = fdot2(H2S(a0, 2), H2S(x, 2), u0a);
        u0b = fdot2(H2S(a0, 3), H2S(x, 3), u0b);
        u1a = fdot2(H2S(a0, 0), H2S(y, 0), u1a);
        u1b = fdot2(H2S(a0, 1), H2S(y, 1), u1b);
        u1a = fdot2(H2S(a0, 2), H2S(y, 2), u1a);
        u1b = fdot2(H2S(a0, 3), H2S(y, 3), u1b);
        a0 = a1; a1 = a2; a2 = a3; a3 = nxt;
      }
    }
    {
      float u0 = u0a + u0b, u1 = u1a + u1b;
      u0 += __shfl_xor(u0, 1, 64);
      u1 += __shfl_xor(u1, 1, 64);
      if (g2 == 0) {
        float z = fminf(fmaxf(2.f * (u0 + b1k), -18.f), 18.f);
        s_arr[0][kL >> 6][kL & 63] = __expf(z);
      } else {
        float z = fminf(fmaxf(2.f * (u1 + b1k), -18.f), 18.f);
        s_arr[1][kL >> 6][kL & 63] = __expf(z);
      }
    }
    // fused W prefetch (chunks 0,1), issued BEFORE the barrier.
    h8 A0 = wb[0], A1r = wb[1], A2 = wb[2], A3 = wb[3];
    h8 B0 = wb[1024], B1 = wb[1025], B2 = wb[1026], B3 = wb[1027];
    bar_lds();  // #1: s_arr visible

    // ---- Fused: split-K Whh (4 gates x 2 batches) + attn scores ----
    float ghA0 = 0.f, ghA1 = 0.f, ghA2 = 0.f, ghA3 = 0.f;  // batch 0, own K-half
    float ghB0 = 0.f, ghB1 = 0.f, ghB2 = 0.f, ghB3 = 0.f;  // batch 1, own K-half
    float accA0 = 0.f, accA1 = 0.f, accB0 = 0.f, accB1 = 0.f;

#define GH8(acc, w, v)                            \
    acc = fdot2(H2S(w, 0), H2S(v, 0), acc);       \
    acc = fdot2(H2S(w, 1), H2S(v, 1), acc);       \
    acc = fdot2(H2S(w, 2), H2S(v, 2), acc);       \
    acc = fdot2(H2S(w, 3), H2S(v, 3), acc);

#define FBODY(C0, C1, C2, C3, II)                                              \
    {                                                                          \
      int ipn = ((II) + 2) & 15;                                               \
      h8 T0 = wb[ipn * 1024 + 0], T1 = wb[ipn * 1024 + 1];                     \
      h8 T2 = wb[ipn * 1024 + 2], T3 = wb[ipn * 1024 + 3];                     \
      h8 x = *(const h8*)(hxb + (II) * 8);          /* batch 0 */              \
      h8 y = *(const h8*)(hxb + 544 + (II) * 8);    /* batch 1 */              \
      GH8(ghA0, C0, x)  GH8(ghB0, C0, y)                                       \
      GH8(ghA1, C1, x)  GH8(ghB1, C1, y)                                       \
      GH8(ghA2, C2, x)  GH8(ghB2, C2, y)                                       \
      GH8(ghA3, C3, x)  GH8(ghB3, C3, y)                                       \
      {                                                                        \
        float4 wv = w2p[(II)];                                                 \
        h4 tv = tpA[(II)];                                                     \
        float4 sv = spA[(II)];                                                 \
        accA0 = fmaf(wv.x, rcp_f(fmaf(sv.x, (float)tv[0], 1.f)), accA0);       \
        accA1 = fmaf(wv.y, rcp_f(fmaf(sv.y, (float)tv[1], 1.f)), accA1);       \
        accA0 = fmaf(wv.z, rcp_f(fmaf(sv.z, (float)tv[2], 1.f)), accA0);       \
        accA1 = fmaf(wv.w, rcp_f(fmaf(sv.w, (float)tv[3], 1.f)), accA1);       \
        h4 tw = tpB[(II)];                                                     \
        float4 sw = spB[(II)];                                                 \
        accB0 = fmaf(wv.x, rcp_f(fmaf(sw.x, (float)tw[0], 1.f)), accB0);       \
        accB1 = fmaf(wv.y, rcp_f(fmaf(sw.y, (float)tw[1], 1.f)), accB1);       \
        accB0 = fmaf(wv.z, rcp_f(fmaf(sw.z, (float)tw[2], 1.f)), accB0);       \
        accB1 = fmaf(wv.w, rcp_f(fmaf(sw.w, (float)tw[3], 1.f)), accB1);       \
      }                                                                        \
      C0 = T0; C1 = T1; C2 = T2; C3 = T3;                                      \
    }

#pragma unroll 1
    for (int ih = 0; ih < 8; ++ih) {
      FBODY(A0, A1r, A2, A3, 2 * ih)
      FBODY(B0, B1, B2, B3, 2 * ih + 1)
    }
#undef FBODY
#undef GH8
    {
      // score = W2sum - 2*Sum w2/(Es*Et+1)  (+ba2), quarters combined by shfl
      float accA = fmaf(-2.f, accA0 + accA1, W2q);
      accA += __shfl_xor(accA, 1, 64);
      accA += __shfl_xor(accA, 2, 64);
      if (g_u == 0) score_s[bbA][jA] = accA + ba2v;
      float accB = fmaf(-2.f, accB0 + accB1, W2q);
      accB += __shfl_xor(accB, 1, 64);
      accB += __shfl_xor(accB, 2, 64);
      if (g_u == 0 && prB < 254) score_s[bbB2][jB2] = accB + ba2v;
    }
    // pair-combine K-halves: lane's own batch is bbE==g2; partner holds
    // the other K-half of my batch in its same-named accumulator.
    float gh0, gh1, gh2, gh3;
    {
      float s0 = g2 ? ghA0 : ghB0, k0 = g2 ? ghB0 : ghA0;
      float s1 = g2 ? ghA1 : ghB1, k1 = g2 ? ghB1 : ghA1;
      float s2 = g2 ? ghA2 : ghB2, k2v = g2 ? ghB2 : ghA2;
      float s3 = g2 ? ghA3 : ghB3, k3 = g2 ? ghB3 : ghA3;
      gh0 = k0 + __shfl_xor(s0, 1, 64);
      gh1 = k1 + __shfl_xor(s1, 1, 64);
      gh2 = k2v + __shfl_xor(s2, 1, 64);
      gh3 = k3 + __shfl_xor(s3, 1, 64);
    }
    bar_lds();  // #2: score_s visible

    // ---- Phase C: redundant per-wave softmax, interleaved reductions ----
    float ytil0, ytil1;
    float ra, rb;
    {
      const int ln = L & 63;
      const int wv = L >> 6;
      float e0a = __expf(score_s[0][ln]);
      float e1a = (ln < 63) ? __expf(score_s[0][64 + ln]) : 0.f;
      float e0b = __expf(score_s[1][ln]);
      float e1b = (ln < 63) ? __expf(score_s[1][64 + ln]) : 0.f;
      float sa = e0a + e1a, sb = e0b + e1b;
      float cwa = e0a * p_s[0][ln] + ((ln < 63) ? e1a * p_s[0][64 + ln] : 0.f);
      float cwb = e0b * p_s[1][ln] + ((ln < 63) ? e1b * p_s[1][64 + ln] : 0.f);
#pragma unroll
      for (int s = 32; s; s >>= 1) {
        sa += __shfl_xor(sa, s, 64);
        sb += __shfl_xor(sb, s, 64);
        cwa += __shfl_xor(cwa, s, 64);
        cwb += __shfl_xor(cwb, s, 64);
      }
      ra = rcp_f(sa); rb = rcp_f(sb);
      if (wv == 0) {
        float* wout = outp + 512 + ((size_t)b0 * T127 + t) * T127;
        wout[ln] = e0a * ra;
        if (ln < 63) wout[64 + ln] = e1a * ra;
      } else if (wv == 1) {
        float* wout = outp + 512 + ((size_t)(b0 + 1) * T127 + t) * T127;
        wout[ln] = e0b * rb;
        if (ln < 63) wout[64 + ln] = e1b * rb;
      }
      ytil0 = cwa * ra + wfcy * yh_s[0][t] + bfc0;
      ytil1 = cwb * rb + wfcy * yh_s[1][t] + bfc0;
      if (t == T127 - 1) {
        float cqa = e0a * q_s[0][ln] + ((ln < 63) ? e1a * q_s[0][64 + ln] : 0.f);
        float cqb = e0b * q_s[1][ln] + ((ln < 63) ? e1b * q_s[1][64 + ln] : 0.f);
#pragma unroll
        for (int s = 32; s; s >>= 1) {
          cqa += __shfl_xor(cqa, s, 64);
          cqb += __shfl_xor(cqb, s, 64);
        }
        if (L == 0) { ctxq_s[0] = cqa * ra; ctxq_s[1] = cqb * rb; }
      }
    }

    // ---- Phase D+E fused: gates + cell update, all in-lane ----
    {
      float yt = bbE ? ytil1 : ytil0;
      float g_i = gh0 + wih0 * yt + bia0;
      float g_f = gh1 + wih1 * yt + bia1;
      float g_g = gh2 + wih2 * yt + bia2;
      float g_o = gh3 + wih3 * yt + bia3;
      float ai = fast_sig(g_i);
      float af = fast_sig(g_f);
      float ag = fast_tanh(g_g);
      float ao = fast_sig(g_o);
      float cn = af * c_reg + ai * ag;
      float hn = ao * fast_tanh(cn);
      c_reg = cn;
      hch[bbE][kk2 >> 7][kk2 & 127] = (f16)hn;
      hch[bbE][2 + (kk2 >> 7)][kk2 & 127] = (f16)cn;
      if (t == T127 - 1) {
        float po = wfcf_k * hn;
        po += __shfl_xor(po, 32, 64);
        po += __shfl_xor(po, 16, 64);
        po += __shfl_xor(po, 8, 64);
        po += __shfl_xor(po, 4, 64);
        po += __shfl_xor(po, 2, 64);
        if ((L & 63) < 2) red2[(L >> 6) * 2 + (L & 1)] = po;
      }
    }
    bar_lds();  // #3: hch (+ red2/ctxq on last step) visible
  }

  // ---------------- final: out = Wfcf[0:256].h + ctx.Wfcf[256:512] + b ----------------
  if (L < 2) {
    float o = ctxq_s[L] + bfcf[0];
#pragma unroll
    for (int w = 0; w < 8; ++w) o += red2[w * 2 + L];
    outp[b0 + L] = o;
  }
}

extern "C" void kernel_launch(void* const* d_in, const int* in_sizes, int n_in,
                              void* d_out, int out_size, void* d_ws, size_t ws_size,
                              hipStream_t stream) {
  (void)in_sizes; (void)n_in; (void)out_size; (void)ws_size;
  f16* wsU = (f16*)d_ws;            // 32*512*8 = 131072 halves (256 KiB)
  f16* wsH = wsU + 131072;          // 32*256*4*8 = 262144 halves (512 KiB)
  pack_wsU<<<64, 256, 0, stream>>>((const float*)d_in[2], wsU);
  pack_wsH<<<128, 256, 0, stream>>>((const float*)d_in[7], wsH);
  decoder_kernel<<<256, 512, 0, stream>>>(
      (const float*)d_in[0], (const float*)d_in[1], (const float*)d_in[2],
      (const float*)d_in[3], (const float*)d_in[4], (const float*)d_in[5],
      (const float*)d_in[6], (const float*)d_in[8], (const float*)d_in[9],
      (const float*)d_in[10], (const float*)d_in[11], (const float*)d_in[12],
      (const float*)d_in[13], wsU, wsH, (float*)d_out);
}